// Round 15
// baseline (168.284 us; speedup 1.0000x reference)
//
#include <hip/hip_runtime.h>
#include <hip/hip_fp16.h>

// GCN layer on MI355X — CSR-gather, atomic-free CSR build, fp16 MFMA GEMM.
// out[c] = dis[c] * ( sum_{e: dst=c} t2[src_e] + t2[c] ) + bias
// t2[i] = dis[i] * (x @ W)[i], dis[i] = rsqrt(1 + outdeg(i)).
//
// Round-14 post-mortem: gather is at its L2-miss service floor (~32us, 93MB
// @ ~3TB/s): MLP probes r8/r14 neutral, slice probe r13 3x worse. Gather
// frozen at the r11 form. This round consolidates the build: k_scan1 deleted
// (hist -> [blk][bin]; part/bucket reconstruct cursor bases via per-bin
// prefix loops over the L2-resident hist + LDS scan of totals), and
// k_bucket's fine loops vectorized (uchar4/int4 with alignment pro/epilogue).
// 5 kernels total.

#define EPB 4096  // edges per k_hist/k_part block

typedef _Float16 f16;
typedef f16 f16x8 __attribute__((ext_vector_type(8)));
typedef float f32x4 __attribute__((ext_vector_type(4)));

static inline int cdiv(int a, int b) { return (a + b - 1) / b; }

// P1: coarse histograms, layout hist[blk*nbins + bin] (dst) and
// hist[HALF + blk*nbins + bin] (src), HALF = nblk*nbins. Coalesced writes.
// Blocks 0..63 also transpose W -> WhT fp16 (256 elems each, parallel).
__global__ __launch_bounds__(256) void k_hist(const int* __restrict__ ei, int E,
                                              int* __restrict__ hist, int nblk, int nbins,
                                              const float* __restrict__ W,
                                              f16* __restrict__ WhT) {
  __shared__ int ha[256], hb[256];
  const int tid = threadIdx.x, blk = blockIdx.x;
  const int HALF = nblk * nbins;
  ha[tid] = 0; hb[tid] = 0;
  __syncthreads();
  const int base = blk * EPB;
  const int lim = min(EPB, E - base);
  if ((E & 3) == 0) {
    for (int i = tid * 4; i + 3 < lim; i += 1024) {
      int4 s4 = *(const int4*)(ei + base + i);
      int4 d4 = *(const int4*)(ei + E + base + i);
      atomicAdd(&ha[d4.x >> 8], 1); atomicAdd(&hb[s4.x >> 8], 1);
      atomicAdd(&ha[d4.y >> 8], 1); atomicAdd(&hb[s4.y >> 8], 1);
      atomicAdd(&ha[d4.z >> 8], 1); atomicAdd(&hb[s4.z >> 8], 1);
      atomicAdd(&ha[d4.w >> 8], 1); atomicAdd(&hb[s4.w >> 8], 1);
    }
    for (int i = (lim & ~3) + tid; i < lim; i += 256) {
      atomicAdd(&ha[ei[E + base + i] >> 8], 1);
      atomicAdd(&hb[ei[base + i] >> 8], 1);
    }
  } else {
    for (int i = tid; i < lim; i += 256) {
      atomicAdd(&ha[ei[E + base + i] >> 8], 1);
      atomicAdd(&hb[ei[base + i] >> 8], 1);
    }
  }
  if (blk < 64) {  // W[k][c] -> WhT[c][k], 64 blocks x 256 = 16384 elems
    int i = blk * 256 + tid;
    int k = i >> 7, c = i & 127;
    WhT[c * 128 + k] = (f16)W[i];
  }
  __syncthreads();
  if (tid < nbins) {
    hist[blk * nbins + tid] = ha[tid];
    hist[HALF + blk * nbins + tid] = hb[tid];
  }
}

// P2: partition edges into coarse buckets. Cursor bases reconstructed
// in-kernel: per-bin prefix over hist rows [0,blk) + LDS scan of totals.
// ebA[posA] = (src<<8)|(dst&255), ebB[posB] = src&255 (uchar).
__global__ __launch_bounds__(256) void k_part(const int* __restrict__ ei, int E,
                                              const int* __restrict__ hist,
                                              int nblk, int nbins,
                                              int* __restrict__ ebA,
                                              unsigned char* __restrict__ ebB) {
  __shared__ int cA[256], cB[256], sA[256], sB[256];
  const int tid = threadIdx.x, blk = blockIdx.x;
  const int HALF = nblk * nbins;

  int preA = 0, preB = 0, runA = 0, runB = 0;
  if (tid < nbins) {
    for (int j = 0; j < blk; ++j) {
      preA += hist[j * nbins + tid];
      preB += hist[HALF + j * nbins + tid];
    }
    runA = preA; runB = preB;
    for (int j = blk; j < nblk; ++j) {
      runA += hist[j * nbins + tid];
      runB += hist[HALF + j * nbins + tid];
    }
  }
  // runA/runB = tot(bin=tid); exclusive scan across bins
  sA[tid] = (tid < nbins) ? runA : 0;
  sB[tid] = (tid < nbins) ? runB : 0;
  __syncthreads();
  int vA = sA[tid], vB = sB[tid];
#pragma unroll
  for (int off = 1; off < 256; off <<= 1) {
    int aA = (tid >= off) ? sA[tid - off] : 0;
    int aB = (tid >= off) ? sB[tid - off] : 0;
    __syncthreads();
    sA[tid] += aA; sB[tid] += aB;
    __syncthreads();
  }
  if (tid < nbins) {
    cA[tid] = (sA[tid] - vA) + preA;  // baseA(bin) + prefix within bin
    cB[tid] = (sB[tid] - vB) + preB;
  }
  __syncthreads();

  const int base = blk * EPB;
  const int lim = min(EPB, E - base);
  if ((E & 3) == 0) {
    for (int i = tid * 4; i + 3 < lim; i += 1024) {
      int4 s4 = *(const int4*)(ei + base + i);
      int4 d4 = *(const int4*)(ei + E + base + i);
      int pa, pb;
      pa = atomicAdd(&cA[d4.x >> 8], 1); ebA[pa] = (s4.x << 8) | (d4.x & 255);
      pb = atomicAdd(&cB[s4.x >> 8], 1); ebB[pb] = (unsigned char)(s4.x & 255);
      pa = atomicAdd(&cA[d4.y >> 8], 1); ebA[pa] = (s4.y << 8) | (d4.y & 255);
      pb = atomicAdd(&cB[s4.y >> 8], 1); ebB[pb] = (unsigned char)(s4.y & 255);
      pa = atomicAdd(&cA[d4.z >> 8], 1); ebA[pa] = (s4.z << 8) | (d4.z & 255);
      pb = atomicAdd(&cB[s4.z >> 8], 1); ebB[pb] = (unsigned char)(s4.z & 255);
      pa = atomicAdd(&cA[d4.w >> 8], 1); ebA[pa] = (s4.w << 8) | (d4.w & 255);
      pb = atomicAdd(&cB[s4.w >> 8], 1); ebB[pb] = (unsigned char)(s4.w & 255);
    }
    for (int i = (lim & ~3) + tid; i < lim; i += 256) {
      int s = ei[base + i], d = ei[E + base + i];
      int pa = atomicAdd(&cA[d >> 8], 1); ebA[pa] = (s << 8) | (d & 255);
      int pb = atomicAdd(&cB[s >> 8], 1); ebB[pb] = (unsigned char)(s & 255);
    }
  } else {
    for (int i = tid; i < lim; i += 256) {
      int s = ei[base + i], d = ei[E + base + i];
      int pa = atomicAdd(&cA[d >> 8], 1); ebA[pa] = (s << 8) | (d & 255);
      int pb = atomicAdd(&cB[s >> 8], 1); ebB[pb] = (unsigned char)(s & 255);
    }
  }
}

// P3 merged: per coarse bucket b,
//  phase 1 (deg): fine count of src over ebB bucket -> dis = rsqrt(1+cnt)
//  phase 2 (csr): fine count+scan of dst over ebA bucket -> offs, place srcs
// Bucket bounds reconstructed (totals loop + LDS scan). Fine loops
// vectorized uchar4/int4. srcs stored PRE-SCALED by 64 (half2-row units).
__global__ __launch_bounds__(256) void k_bucket(
    const int* __restrict__ ebA, const unsigned char* __restrict__ ebB,
    const int* __restrict__ hist, int nblk, int nbins, int E,
    float* __restrict__ dis, int* __restrict__ offs,
    int* __restrict__ srcs, int N) {
  __shared__ int h[256], tmp[256], cur[256];
  __shared__ int baseA[256], totA[256], baseB[256], totB[256];
  const int tid = threadIdx.x, b = blockIdx.x;
  const int HALF = nblk * nbins;
  const int node = b * 256 + tid;

  // reconstruct bucket bases: totals per bin + exclusive scan
  int runA = 0, runB = 0;
  if (tid < nbins) {
    for (int j = 0; j < nblk; ++j) {
      runA += hist[j * nbins + tid];
      runB += hist[HALF + j * nbins + tid];
    }
  }
  baseA[tid] = (tid < nbins) ? runA : 0;
  baseB[tid] = (tid < nbins) ? runB : 0;
  totA[tid] = runA; totB[tid] = runB;
  __syncthreads();
  int vA = baseA[tid], vB = baseB[tid];
#pragma unroll
  for (int off = 1; off < 256; off <<= 1) {
    int aA = (tid >= off) ? baseA[tid - off] : 0;
    int aB = (tid >= off) ? baseB[tid - off] : 0;
    __syncthreads();
    baseA[tid] += aA; baseB[tid] += aB;
    __syncthreads();
  }
  baseA[tid] -= vA;  // exclusive
  baseB[tid] -= vB;
  __syncthreads();

  // --- phase 1: out-degree over ebB bucket -> dis ---
  {
    const int bs = baseB[b];
    const int be = bs + totB[b];
    h[tid] = 0;
    __syncthreads();
    int bs_al = (bs + 3) & ~3;
    if (bs_al > be) bs_al = be;
    if (tid < bs_al - bs) atomicAdd(&h[ebB[bs + tid]], 1);
    const int vend = bs_al + ((be - bs_al) & ~3);
    for (int j = bs_al + tid * 4; j < vend; j += 1024) {
      uchar4 v = *(const uchar4*)(ebB + j);
      atomicAdd(&h[v.x], 1); atomicAdd(&h[v.y], 1);
      atomicAdd(&h[v.z], 1); atomicAdd(&h[v.w], 1);
    }
    if (tid < be - vend) atomicAdd(&h[ebB[vend + tid]], 1);
    __syncthreads();
    if (node < N) dis[node] = rsqrtf(1.0f + (float)h[tid]);
    __syncthreads();
  }

  // --- phase 2: CSR offs + srcs over ebA bucket ---
  {
    const int bs = baseA[b];
    const int be = bs + totA[b];
    h[tid] = 0;
    __syncthreads();
    int bs_al = (bs + 3) & ~3;
    if (bs_al > be) bs_al = be;
    if (tid < bs_al - bs) atomicAdd(&h[ebA[bs + tid] & 255], 1);
    const int vend = bs_al + ((be - bs_al) & ~3);
    for (int j = bs_al + tid * 4; j < vend; j += 1024) {
      int4 v = *(const int4*)(ebA + j);
      atomicAdd(&h[v.x & 255], 1); atomicAdd(&h[v.y & 255], 1);
      atomicAdd(&h[v.z & 255], 1); atomicAdd(&h[v.w & 255], 1);
    }
    if (tid < be - vend) atomicAdd(&h[ebA[vend + tid] & 255], 1);
    __syncthreads();
    int cnt = h[tid];
    tmp[tid] = cnt;
    __syncthreads();
#pragma unroll
    for (int off = 1; off < 256; off <<= 1) {
      int add = (tid >= off) ? tmp[tid - off] : 0;
      __syncthreads();
      tmp[tid] += add;
      __syncthreads();
    }
    int gpos = bs + tmp[tid] - cnt;
    if (node < N) offs[node] = gpos;
    cur[tid] = gpos;
    __syncthreads();
    if (tid < bs_al - bs) {
      int v = ebA[bs + tid];
      int p = atomicAdd(&cur[v & 255], 1);
      srcs[p] = (v >> 8) << 6;
    }
    for (int j = bs_al + tid * 4; j < vend; j += 1024) {
      int4 v = *(const int4*)(ebA + j);
      int p;
      p = atomicAdd(&cur[v.x & 255], 1); srcs[p] = (v.x >> 8) << 6;
      p = atomicAdd(&cur[v.y & 255], 1); srcs[p] = (v.y >> 8) << 6;
      p = atomicAdd(&cur[v.z & 255], 1); srcs[p] = (v.z >> 8) << 6;
      p = atomicAdd(&cur[v.w & 255], 1); srcs[p] = (v.w >> 8) << 6;
    }
    if (tid < be - vend) {
      int v = ebA[vend + tid];
      int p = atomicAdd(&cur[v & 255], 1);
      srcs[p] = (v >> 8) << 6;
    }
    if (b == 0 && tid == 0) offs[N] = E;
  }
}

// MFMA GEMM: t2h[r][c] = fp16( dis[r] * sum_k x[r][k] * W[k][c] ).
// 256 thr = 4 waves; wave w owns rows [blk*64 + w*16, +16), all 128 cols.
// C/D layout: col = lane&15, row = (lane>>4)*4 + reg  [guide §3, m89].
__global__ __launch_bounds__(256) void k_gemm_mfma(
    const float* __restrict__ x, const f16* __restrict__ WhT,
    const float* __restrict__ dis, __half* __restrict__ t2h, int N) {
  __shared__ __align__(16) f16 cs[4][16][136];  // stride 272B = 17x16B
  const int tid = threadIdx.x;
  const int w = tid >> 6, l = tid & 63;
  const int l15 = l & 15, lg = l >> 4;
  const int wr0 = blockIdx.x * 64 + w * 16;
  const int arow = wr0 + l15;
  const bool avalid = arow < N;

  f32x4 acc[8];
#pragma unroll
  for (int ct = 0; ct < 8; ++ct) acc[ct] = (f32x4){0.f, 0.f, 0.f, 0.f};

#pragma unroll
  for (int kc = 0; kc < 4; ++kc) {
    f16x8 af;
    if (avalid) {
      const float4* ap = (const float4*)(x + (size_t)arow * 128 + kc * 32 + lg * 8);
      float4 a0 = ap[0], a1 = ap[1];
      af[0] = (f16)a0.x; af[1] = (f16)a0.y; af[2] = (f16)a0.z; af[3] = (f16)a0.w;
      af[4] = (f16)a1.x; af[5] = (f16)a1.y; af[6] = (f16)a1.z; af[7] = (f16)a1.w;
    } else {
#pragma unroll
      for (int j = 0; j < 8; ++j) af[j] = (f16)0.f;
    }
#pragma unroll
    for (int ct = 0; ct < 8; ++ct) {
      f16x8 bf = *(const f16x8*)(WhT + (ct * 16 + l15) * 128 + kc * 32 + lg * 8);
      acc[ct] = __builtin_amdgcn_mfma_f32_16x16x32_f16(af, bf, acc[ct], 0, 0, 0);
    }
  }

  // scale rows by dis and stash (transposed per-wave) in LDS
  float d4[4];
#pragma unroll
  for (int j = 0; j < 4; ++j) {
    int r = wr0 + lg * 4 + j;
    d4[j] = (r < N) ? dis[r] : 0.f;
  }
#pragma unroll
  for (int ct = 0; ct < 8; ++ct)
#pragma unroll
    for (int j = 0; j < 4; ++j)
      cs[w][lg * 4 + j][ct * 16 + l15] = (f16)(d4[j] * acc[ct][j]);
  __syncthreads();

  // coalesced write-out: 4 iters x 64 lanes x 16B
#pragma unroll
  for (int it = 0; it < 4; ++it) {
    int t = it * 64 + l;
    int row = t >> 4, seg = t & 15;
    int gr = wr0 + row;
    if (gr < N)
      *(f16x8*)((f16*)t2h + (size_t)gr * 128 + seg * 8) = *(const f16x8*)&cs[w][row][seg * 8];
  }
}

// One 64-lane wave per node; lane owns __half2 at col=lane*2 (r11-proven,
// frozen). srcs entries are pre-scaled (src*64) half2-row offsets.
__global__ __launch_bounds__(256) void k_gather(
    const int* __restrict__ offs, const int* __restrict__ srcs,
    const __half* __restrict__ t2h, const float* __restrict__ dis,
    const float* __restrict__ bias, float* __restrict__ out, int N) {
  const int node = blockIdx.x * 4 + (threadIdx.x >> 6);
  const int lane = threadIdx.x & 63;
  if (node >= N) return;

  const int s = offs[node];
  const int e = offs[node + 1];
  const __half2* t2v = (const __half2*)t2h;

  float2 acc = __half22float2(t2v[(size_t)node * 64 + lane]);  // self loop
  float2 acc2 = make_float2(0.f, 0.f);
  int j = s;
  for (; j + 7 < e; j += 8) {
    int s0 = srcs[j], s1 = srcs[j + 1], s2 = srcs[j + 2], s3 = srcs[j + 3];
    int s4 = srcs[j + 4], s5 = srcs[j + 5], s6 = srcs[j + 6], s7 = srcs[j + 7];
    float2 v0 = __half22float2(t2v[(size_t)s0 + lane]);
    float2 v1 = __half22float2(t2v[(size_t)s1 + lane]);
    float2 v2 = __half22float2(t2v[(size_t)s2 + lane]);
    float2 v3 = __half22float2(t2v[(size_t)s3 + lane]);
    float2 v4 = __half22float2(t2v[(size_t)s4 + lane]);
    float2 v5 = __half22float2(t2v[(size_t)s5 + lane]);
    float2 v6 = __half22float2(t2v[(size_t)s6 + lane]);
    float2 v7 = __half22float2(t2v[(size_t)s7 + lane]);
    acc.x += (v0.x + v1.x) + (v2.x + v3.x);
    acc.y += (v0.y + v1.y) + (v2.y + v3.y);
    acc2.x += (v4.x + v5.x) + (v6.x + v7.x);
    acc2.y += (v4.y + v5.y) + (v6.y + v7.y);
  }
  for (; j + 3 < e; j += 4) {
    int s0 = srcs[j], s1 = srcs[j + 1], s2 = srcs[j + 2], s3 = srcs[j + 3];
    float2 v0 = __half22float2(t2v[(size_t)s0 + lane]);
    float2 v1 = __half22float2(t2v[(size_t)s1 + lane]);
    float2 v2 = __half22float2(t2v[(size_t)s2 + lane]);
    float2 v3 = __half22float2(t2v[(size_t)s3 + lane]);
    acc.x += (v0.x + v1.x) + (v2.x + v3.x);
    acc.y += (v0.y + v1.y) + (v2.y + v3.y);
  }
  for (; j < e; ++j) {
    float2 v = __half22float2(t2v[(size_t)srcs[j] + lane]);
    acc.x += v.x;
    acc.y += v.y;
  }
  acc.x += acc2.x;
  acc.y += acc2.y;

  const float dn = dis[node];
  const float2 b = *(const float2*)(bias + (size_t)lane * 2);
  float2 r = make_float2(dn * acc.x + b.x, dn * acc.y + b.y);
  *(float2*)(out + (size_t)node * 128 + (size_t)lane * 2) = r;
}

extern "C" void kernel_launch(void* const* d_in, const int* in_sizes, int n_in,
                              void* d_out, int out_size, void* d_ws, size_t ws_size,
                              hipStream_t stream) {
  const float* x = (const float*)d_in[0];
  const int* ei = (const int*)d_in[1];   // int64 in reference, int32 on device: [2,E] flat
  const float* W = (const float*)d_in[2];
  const float* bias = (const float*)d_in[3];
  float* out = (float*)d_out;

  const int N = in_sizes[0] / 128;
  const int E = in_sizes[1] / 2;
  const int NBLK = cdiv(E, EPB);    // edge blocks (196)
  const int NBINS = cdiv(N, 256);   // coarse node buckets (196), must be <=256
  const int M = 2 * NBLK * NBINS;   // hist length (both halves)

  // Workspace. Overlay region (hist|ebA|ebB ~4.4MB) aliases t2h (12.8MB):
  // dead before k_gemm_mfma writes t2h. dis/offs/srcs/WhT outside overlay.
  __half* t2h = (__half*)d_ws;
  int* hist = (int*)d_ws;                      // [M] = [2][NBLK][NBINS]
  int* ebA = hist + M;                         // [E]  (src<<8)|(dst&255), dst-bucketed
  unsigned char* ebB = (unsigned char*)(ebA + E);  // [E] src&255, src-bucketed
  float* dis = (float*)(t2h + (size_t)N * 128);    // [N]
  int* offs = (int*)(dis + N);                 // [N+1]
  int* srcs = offs + (N + 1);                  // [E] pre-scaled src*64
  f16* WhT = (f16*)(srcs + E);                 // [128*128] fp16 B^T

  k_hist<<<NBLK, 256, 0, stream>>>(ei, E, hist, NBLK, NBINS, W, WhT);
  k_part<<<NBLK, 256, 0, stream>>>(ei, E, hist, NBLK, NBINS, ebA, ebB);
  k_bucket<<<NBINS, 256, 0, stream>>>(ebA, ebB, hist, NBLK, NBINS, E,
                                      dis, offs, srcs, N);
  k_gemm_mfma<<<cdiv(N, 64), 256, 0, stream>>>(x, WhT, dis, t2h, N);
  k_gather<<<cdiv(N, 4), 256, 0, stream>>>(offs, srcs, t2h, dis, bias, out, N);
}

// Round 16
// 92.719 us; speedup vs baseline: 1.8150x; 1.8150x over previous
//
#include <hip/hip_runtime.h>
#include <hip/hip_fp16.h>

// GCN layer on MI355X — CSR-gather, atomic-free CSR build, fp16 MFMA GEMM.
// out[c] = dis[c] * ( sum_{e: dst=c} t2[src_e] + t2[c] ) + bias
// t2[i] = dis[i] * (x @ W)[i], dis[i] = rsqrt(1 + outdeg(i)).
//
// Round-15 post-mortem: scan-free cursor reconstruction made k_part 72us
// (196-deep per-thread load chain at VGPR=8, unpipelined). REVERTED to the
// r11 chain (100.2us proven: hist[bin][blk] + scan1 + LDS scan_partials).
// Kept only r15's untested component: k_bucket fine loops vectorized
// (uchar4/int4, alignment pro/epilogue). 6 kernels.

#define EPB 4096  // edges per k_hist/k_part block

typedef _Float16 f16;
typedef f16 f16x8 __attribute__((ext_vector_type(8)));
typedef float f32x4 __attribute__((ext_vector_type(4)));

static inline int cdiv(int a, int b) { return (a + b - 1) / b; }

// P1: coarse histograms, transposed layout hist[bin*nblk + blk] (dst) and
// hist[HALF + bin*nblk + blk] (src), HALF = nbins*nblk.
// Blocks 0..63 also transpose W -> WhT fp16 (256 elems each, parallel).
__global__ __launch_bounds__(256) void k_hist(const int* __restrict__ ei, int E,
                                              int* __restrict__ hist, int nblk, int nbins,
                                              const float* __restrict__ W,
                                              f16* __restrict__ WhT) {
  __shared__ int ha[256], hb[256];
  const int tid = threadIdx.x, blk = blockIdx.x;
  ha[tid] = 0; hb[tid] = 0;
  __syncthreads();
  const int base = blk * EPB;
  const int lim = min(EPB, E - base);
  if ((E & 3) == 0) {
    for (int i = tid * 4; i + 3 < lim; i += 1024) {
      int4 s4 = *(const int4*)(ei + base + i);
      int4 d4 = *(const int4*)(ei + E + base + i);
      atomicAdd(&ha[d4.x >> 8], 1); atomicAdd(&hb[s4.x >> 8], 1);
      atomicAdd(&ha[d4.y >> 8], 1); atomicAdd(&hb[s4.y >> 8], 1);
      atomicAdd(&ha[d4.z >> 8], 1); atomicAdd(&hb[s4.z >> 8], 1);
      atomicAdd(&ha[d4.w >> 8], 1); atomicAdd(&hb[s4.w >> 8], 1);
    }
    for (int i = (lim & ~3) + tid; i < lim; i += 256) {
      atomicAdd(&ha[ei[E + base + i] >> 8], 1);
      atomicAdd(&hb[ei[base + i] >> 8], 1);
    }
  } else {
    for (int i = tid; i < lim; i += 256) {
      atomicAdd(&ha[ei[E + base + i] >> 8], 1);
      atomicAdd(&hb[ei[base + i] >> 8], 1);
    }
  }
  if (blk < 64) {  // W[k][c] -> WhT[c][k], 64 blocks x 256 = 16384 elems
    int i = blk * 256 + tid;
    int k = i >> 7, c = i & 127;
    WhT[c * 128 + k] = (f16)W[i];
  }
  __syncthreads();
  if (tid < nbins) {
    hist[tid * nblk + blk] = ha[tid];
    hist[nbins * nblk + tid * nblk + blk] = hb[tid];
  }
}

// Hierarchical exclusive scan stage 1 (in place), 1024 elems/block.
// partials keeps RAW block sums; consumers scan them in LDS themselves.
__global__ __launch_bounds__(256) void k_scan1(int* __restrict__ a,
                                               int* __restrict__ partials, int M) {
  __shared__ int ws[256];
  const int tid = threadIdx.x;
  const int i0 = blockIdx.x * 1024 + tid * 4;
  int v0 = (i0 + 0 < M) ? a[i0 + 0] : 0;
  int v1 = (i0 + 1 < M) ? a[i0 + 1] : 0;
  int v2 = (i0 + 2 < M) ? a[i0 + 2] : 0;
  int v3 = (i0 + 3 < M) ? a[i0 + 3] : 0;
  int tsum = v0 + v1 + v2 + v3;
  ws[tid] = tsum;
  __syncthreads();
#pragma unroll
  for (int off = 1; off < 256; off <<= 1) {
    int add = (tid >= off) ? ws[tid - off] : 0;
    __syncthreads();
    ws[tid] += add;
    __syncthreads();
  }
  int texcl = ws[tid] - tsum;
  if (tid == 255) partials[blockIdx.x] = ws[255];
  if (i0 + 0 < M) a[i0 + 0] = texcl;
  if (i0 + 1 < M) a[i0 + 1] = texcl + v0;
  if (i0 + 2 < M) a[i0 + 2] = texcl + v0 + v1;
  if (i0 + 3 < M) a[i0 + 3] = texcl + v0 + v1 + v2;
}

// Shared helper: exclusive-scan nb1 (<=256) raw partials into shP.
__device__ __forceinline__ void scan_partials(const int* __restrict__ partials,
                                              int nb1, int* shP, int tid) {
  int v = (tid < nb1) ? partials[tid] : 0;
  shP[tid] = v;
  __syncthreads();
#pragma unroll
  for (int off = 1; off < 256; off <<= 1) {
    int add = (tid >= off) ? shP[tid - off] : 0;
    __syncthreads();
    shP[tid] += add;
    __syncthreads();
  }
  int excl = shP[tid] - v;
  __syncthreads();
  shP[tid] = excl;
  __syncthreads();
}

// P2: partition edges into coarse buckets. ebA[posA] = (src<<8)|(dst&255)
// (dst-bucketed), ebB[posB] = src&255 (src-bucketed, uchar). Plain stores only.
__global__ __launch_bounds__(256) void k_part(const int* __restrict__ ei, int E,
                                              const int* __restrict__ hist,
                                              const int* __restrict__ partials, int nb1,
                                              int nblk, int nbins,
                                              int* __restrict__ ebA,
                                              unsigned char* __restrict__ ebB) {
  __shared__ int cA[256], cB[256], shP[256];
  const int tid = threadIdx.x, blk = blockIdx.x;
  const int HALF = nbins * nblk;
  scan_partials(partials, nb1, shP, tid);
  if (tid < nbins) {
    int ia = tid * nblk + blk;
    int ib = HALF + tid * nblk + blk;
    cA[tid] = hist[ia] + shP[ia >> 10];
    cB[tid] = hist[ib] + shP[ib >> 10] - E;
  }
  __syncthreads();
  const int base = blk * EPB;
  const int lim = min(EPB, E - base);
  if ((E & 3) == 0) {
    for (int i = tid * 4; i + 3 < lim; i += 1024) {
      int4 s4 = *(const int4*)(ei + base + i);
      int4 d4 = *(const int4*)(ei + E + base + i);
      int pa, pb;
      pa = atomicAdd(&cA[d4.x >> 8], 1); ebA[pa] = (s4.x << 8) | (d4.x & 255);
      pb = atomicAdd(&cB[s4.x >> 8], 1); ebB[pb] = (unsigned char)(s4.x & 255);
      pa = atomicAdd(&cA[d4.y >> 8], 1); ebA[pa] = (s4.y << 8) | (d4.y & 255);
      pb = atomicAdd(&cB[s4.y >> 8], 1); ebB[pb] = (unsigned char)(s4.y & 255);
      pa = atomicAdd(&cA[d4.z >> 8], 1); ebA[pa] = (s4.z << 8) | (d4.z & 255);
      pb = atomicAdd(&cB[s4.z >> 8], 1); ebB[pb] = (unsigned char)(s4.z & 255);
      pa = atomicAdd(&cA[d4.w >> 8], 1); ebA[pa] = (s4.w << 8) | (d4.w & 255);
      pb = atomicAdd(&cB[s4.w >> 8], 1); ebB[pb] = (unsigned char)(s4.w & 255);
    }
    for (int i = (lim & ~3) + tid; i < lim; i += 256) {
      int s = ei[base + i], d = ei[E + base + i];
      int pa = atomicAdd(&cA[d >> 8], 1); ebA[pa] = (s << 8) | (d & 255);
      int pb = atomicAdd(&cB[s >> 8], 1); ebB[pb] = (unsigned char)(s & 255);
    }
  } else {
    for (int i = tid; i < lim; i += 256) {
      int s = ei[base + i], d = ei[E + base + i];
      int pa = atomicAdd(&cA[d >> 8], 1); ebA[pa] = (s << 8) | (d & 255);
      int pb = atomicAdd(&cB[s >> 8], 1); ebB[pb] = (unsigned char)(s & 255);
    }
  }
}

// P3 merged: per coarse bucket b,
//  phase 1 (deg): fine count of src over ebB bucket -> dis = rsqrt(1+cnt)
//  phase 2 (csr): fine count+scan of dst over ebA bucket -> offs, place srcs
// Fine loops vectorized uchar4/int4 (alignment pro/epilogue).
// srcs stored PRE-SCALED by 64 (half2-row units) for the gather.
__global__ __launch_bounds__(256) void k_bucket(
    const int* __restrict__ ebA, const unsigned char* __restrict__ ebB,
    const int* __restrict__ hist, const int* __restrict__ partials, int nb1,
    int nblk, int nbins, int E,
    float* __restrict__ dis, int* __restrict__ offs,
    int* __restrict__ srcs, int N) {
  __shared__ int h[256], tmp[256], cur[256], shP[256];
  const int tid = threadIdx.x, b = blockIdx.x;
  const int HALF = nbins * nblk;
  const int node = b * 256 + tid;
  scan_partials(partials, nb1, shP, tid);

  // --- phase 1: out-degree over ebB bucket -> dis ---
  {
    int i0 = HALF + b * nblk;
    const int bs = hist[i0] + shP[i0 >> 10] - E;
    int be = E;
    if (b + 1 < nbins) {
      int i1 = HALF + (b + 1) * nblk;
      be = hist[i1] + shP[i1 >> 10] - E;
    }
    h[tid] = 0;
    __syncthreads();
    int bs_al = (bs + 3) & ~3;
    if (bs_al > be) bs_al = be;
    if (tid < bs_al - bs) atomicAdd(&h[ebB[bs + tid]], 1);
    const int vend = bs_al + ((be - bs_al) & ~3);
    for (int j = bs_al + tid * 4; j < vend; j += 1024) {
      uchar4 v = *(const uchar4*)(ebB + j);
      atomicAdd(&h[v.x], 1); atomicAdd(&h[v.y], 1);
      atomicAdd(&h[v.z], 1); atomicAdd(&h[v.w], 1);
    }
    if (tid < be - vend) atomicAdd(&h[ebB[vend + tid]], 1);
    __syncthreads();
    if (node < N) dis[node] = rsqrtf(1.0f + (float)h[tid]);
    __syncthreads();
  }

  // --- phase 2: CSR offs + srcs over ebA bucket ---
  {
    int i0 = b * nblk;
    const int bs = hist[i0] + shP[i0 >> 10];
    int be = E;
    if (b + 1 < nbins) {
      int i1 = (b + 1) * nblk;
      be = hist[i1] + shP[i1 >> 10];
    }
    h[tid] = 0;
    __syncthreads();
    int bs_al = (bs + 3) & ~3;
    if (bs_al > be) bs_al = be;
    if (tid < bs_al - bs) atomicAdd(&h[ebA[bs + tid] & 255], 1);
    const int vend = bs_al + ((be - bs_al) & ~3);
    for (int j = bs_al + tid * 4; j < vend; j += 1024) {
      int4 v = *(const int4*)(ebA + j);
      atomicAdd(&h[v.x & 255], 1); atomicAdd(&h[v.y & 255], 1);
      atomicAdd(&h[v.z & 255], 1); atomicAdd(&h[v.w & 255], 1);
    }
    if (tid < be - vend) atomicAdd(&h[ebA[vend + tid] & 255], 1);
    __syncthreads();
    int cnt = h[tid];
    tmp[tid] = cnt;
    __syncthreads();
#pragma unroll
    for (int off = 1; off < 256; off <<= 1) {
      int add = (tid >= off) ? tmp[tid - off] : 0;
      __syncthreads();
      tmp[tid] += add;
      __syncthreads();
    }
    int gpos = bs + tmp[tid] - cnt;
    if (node < N) offs[node] = gpos;
    cur[tid] = gpos;
    __syncthreads();
    if (tid < bs_al - bs) {
      int v = ebA[bs + tid];
      int p = atomicAdd(&cur[v & 255], 1);
      srcs[p] = (v >> 8) << 6;
    }
    for (int j = bs_al + tid * 4; j < vend; j += 1024) {
      int4 v = *(const int4*)(ebA + j);
      int p;
      p = atomicAdd(&cur[v.x & 255], 1); srcs[p] = (v.x >> 8) << 6;
      p = atomicAdd(&cur[v.y & 255], 1); srcs[p] = (v.y >> 8) << 6;
      p = atomicAdd(&cur[v.z & 255], 1); srcs[p] = (v.z >> 8) << 6;
      p = atomicAdd(&cur[v.w & 255], 1); srcs[p] = (v.w >> 8) << 6;
    }
    if (tid < be - vend) {
      int v = ebA[vend + tid];
      int p = atomicAdd(&cur[v & 255], 1);
      srcs[p] = (v >> 8) << 6;
    }
    if (b == 0 && tid == 0) offs[N] = E;
  }
}

// MFMA GEMM: t2h[r][c] = fp16( dis[r] * sum_k x[r][k] * W[k][c] ).
// 256 thr = 4 waves; wave w owns rows [blk*64 + w*16, +16), all 128 cols.
// C/D layout: col = lane&15, row = (lane>>4)*4 + reg  [guide §3, m89].
__global__ __launch_bounds__(256) void k_gemm_mfma(
    const float* __restrict__ x, const f16* __restrict__ WhT,
    const float* __restrict__ dis, __half* __restrict__ t2h, int N) {
  __shared__ __align__(16) f16 cs[4][16][136];  // stride 272B = 17x16B
  const int tid = threadIdx.x;
  const int w = tid >> 6, l = tid & 63;
  const int l15 = l & 15, lg = l >> 4;
  const int wr0 = blockIdx.x * 64 + w * 16;
  const int arow = wr0 + l15;
  const bool avalid = arow < N;

  f32x4 acc[8];
#pragma unroll
  for (int ct = 0; ct < 8; ++ct) acc[ct] = (f32x4){0.f, 0.f, 0.f, 0.f};

#pragma unroll
  for (int kc = 0; kc < 4; ++kc) {
    f16x8 af;
    if (avalid) {
      const float4* ap = (const float4*)(x + (size_t)arow * 128 + kc * 32 + lg * 8);
      float4 a0 = ap[0], a1 = ap[1];
      af[0] = (f16)a0.x; af[1] = (f16)a0.y; af[2] = (f16)a0.z; af[3] = (f16)a0.w;
      af[4] = (f16)a1.x; af[5] = (f16)a1.y; af[6] = (f16)a1.z; af[7] = (f16)a1.w;
    } else {
#pragma unroll
      for (int j = 0; j < 8; ++j) af[j] = (f16)0.f;
    }
#pragma unroll
    for (int ct = 0; ct < 8; ++ct) {
      f16x8 bf = *(const f16x8*)(WhT + (ct * 16 + l15) * 128 + kc * 32 + lg * 8);
      acc[ct] = __builtin_amdgcn_mfma_f32_16x16x32_f16(af, bf, acc[ct], 0, 0, 0);
    }
  }

  // scale rows by dis and stash (transposed per-wave) in LDS
  float d4[4];
#pragma unroll
  for (int j = 0; j < 4; ++j) {
    int r = wr0 + lg * 4 + j;
    d4[j] = (r < N) ? dis[r] : 0.f;
  }
#pragma unroll
  for (int ct = 0; ct < 8; ++ct)
#pragma unroll
    for (int j = 0; j < 4; ++j)
      cs[w][lg * 4 + j][ct * 16 + l15] = (f16)(d4[j] * acc[ct][j]);
  __syncthreads();

  // coalesced write-out: 4 iters x 64 lanes x 16B
#pragma unroll
  for (int it = 0; it < 4; ++it) {
    int t = it * 64 + l;
    int row = t >> 4, seg = t & 15;
    int gr = wr0 + row;
    if (gr < N)
      *(f16x8*)((f16*)t2h + (size_t)gr * 128 + seg * 8) = *(const f16x8*)&cs[w][row][seg * 8];
  }
}

// One 64-lane wave per node; lane owns __half2 at col=lane*2 (r11-proven,
// frozen). srcs entries are pre-scaled (src*64) half2-row offsets.
__global__ __launch_bounds__(256) void k_gather(
    const int* __restrict__ offs, const int* __restrict__ srcs,
    const __half* __restrict__ t2h, const float* __restrict__ dis,
    const float* __restrict__ bias, float* __restrict__ out, int N) {
  const int node = blockIdx.x * 4 + (threadIdx.x >> 6);
  const int lane = threadIdx.x & 63;
  if (node >= N) return;

  const int s = offs[node];
  const int e = offs[node + 1];
  const __half2* t2v = (const __half2*)t2h;

  float2 acc = __half22float2(t2v[(size_t)node * 64 + lane]);  // self loop
  float2 acc2 = make_float2(0.f, 0.f);
  int j = s;
  for (; j + 7 < e; j += 8) {
    int s0 = srcs[j], s1 = srcs[j + 1], s2 = srcs[j + 2], s3 = srcs[j + 3];
    int s4 = srcs[j + 4], s5 = srcs[j + 5], s6 = srcs[j + 6], s7 = srcs[j + 7];
    float2 v0 = __half22float2(t2v[(size_t)s0 + lane]);
    float2 v1 = __half22float2(t2v[(size_t)s1 + lane]);
    float2 v2 = __half22float2(t2v[(size_t)s2 + lane]);
    float2 v3 = __half22float2(t2v[(size_t)s3 + lane]);
    float2 v4 = __half22float2(t2v[(size_t)s4 + lane]);
    float2 v5 = __half22float2(t2v[(size_t)s5 + lane]);
    float2 v6 = __half22float2(t2v[(size_t)s6 + lane]);
    float2 v7 = __half22float2(t2v[(size_t)s7 + lane]);
    acc.x += (v0.x + v1.x) + (v2.x + v3.x);
    acc.y += (v0.y + v1.y) + (v2.y + v3.y);
    acc2.x += (v4.x + v5.x) + (v6.x + v7.x);
    acc2.y += (v4.y + v5.y) + (v6.y + v7.y);
  }
  for (; j + 3 < e; j += 4) {
    int s0 = srcs[j], s1 = srcs[j + 1], s2 = srcs[j + 2], s3 = srcs[j + 3];
    float2 v0 = __half22float2(t2v[(size_t)s0 + lane]);
    float2 v1 = __half22float2(t2v[(size_t)s1 + lane]);
    float2 v2 = __half22float2(t2v[(size_t)s2 + lane]);
    float2 v3 = __half22float2(t2v[(size_t)s3 + lane]);
    acc.x += (v0.x + v1.x) + (v2.x + v3.x);
    acc.y += (v0.y + v1.y) + (v2.y + v3.y);
  }
  for (; j < e; ++j) {
    float2 v = __half22float2(t2v[(size_t)srcs[j] + lane]);
    acc.x += v.x;
    acc.y += v.y;
  }
  acc.x += acc2.x;
  acc.y += acc2.y;

  const float dn = dis[node];
  const float2 b = *(const float2*)(bias + (size_t)lane * 2);
  float2 r = make_float2(dn * acc.x + b.x, dn * acc.y + b.y);
  *(float2*)(out + (size_t)node * 128 + (size_t)lane * 2) = r;
}

extern "C" void kernel_launch(void* const* d_in, const int* in_sizes, int n_in,
                              void* d_out, int out_size, void* d_ws, size_t ws_size,
                              hipStream_t stream) {
  const float* x = (const float*)d_in[0];
  const int* ei = (const int*)d_in[1];   // int64 in reference, int32 on device: [2,E] flat
  const float* W = (const float*)d_in[2];
  const float* bias = (const float*)d_in[3];
  float* out = (float*)d_out;

  const int N = in_sizes[0] / 128;
  const int E = in_sizes[1] / 2;
  const int NBLK = cdiv(E, EPB);    // edge blocks (196)
  const int NBINS = cdiv(N, 256);   // coarse node buckets (196)
  const int M = 2 * NBINS * NBLK;   // concatenated hist length
  const int NB1 = cdiv(M, 1024);    // scan stage-1 blocks (<=256 required)

  // Workspace. Overlay region (hist|partials|ebA|ebB ~4.4MB) aliases t2h
  // (12.8MB): dead before k_gemm_mfma writes t2h. WhT outside overlay.
  __half* t2h = (__half*)d_ws;
  int* hist = (int*)d_ws;                      // [M]
  int* partials = hist + M;                    // [<=256] raw block sums
  int* ebA = partials + 256;                   // [E]  (src<<8)|(dst&255), dst-bucketed
  unsigned char* ebB = (unsigned char*)(ebA + E);  // [E] src&255, src-bucketed
  float* dis = (float*)(t2h + (size_t)N * 128);    // [N]
  int* offs = (int*)(dis + N);                 // [N+1]
  int* srcs = offs + (N + 1);                  // [E] pre-scaled src*64
  f16* WhT = (f16*)(srcs + E);                 // [128*128] fp16 B^T

  k_hist<<<NBLK, 256, 0, stream>>>(ei, E, hist, NBLK, NBINS, W, WhT);
  k_scan1<<<NB1, 256, 0, stream>>>(hist, partials, M);
  k_part<<<NBLK, 256, 0, stream>>>(ei, E, hist, partials, NB1, NBLK, NBINS, ebA, ebB);
  k_bucket<<<NBINS, 256, 0, stream>>>(ebA, ebB, hist, partials, NB1, NBLK, NBINS, E,
                                      dis, offs, srcs, N);
  k_gemm_mfma<<<cdiv(N, 64), 256, 0, stream>>>(x, WhT, dis, t2h, N);
  k_gather<<<cdiv(N, 4), 256, 0, stream>>>(offs, srcs, t2h, dis, bias, out, N);
}